// Round 2
// baseline (501.232 us; speedup 1.0000x reference)
//
#include <hip/hip_runtime.h>
#include <cmath>

// QuantumProjection: out = (tanh(x @ W_pre.T + b_pre)*pi -> 4-qubit circuit -> z) @ W_post.T + b_post
// B=32768, D_IN=D_OUT=2048, N_QUBITS=4, N_LAYERS=2. Pure fp32.
// Traffic floor: 268 MB read (x) + 268 MB write (out) -> ~85 us @ 6.3 TB/s.
//
// R2: split the fused kernel (193 us, 2.1 TB/s, VALUBusy 17%, occ 19% -> latency-bound)
// into three lean kernels:
//   A  dots:    s[B][4] = x @ W_pre.T          (read-streamer, 4 rows/wave, W in regs)
//   A2 circuit: z[B][4] = circuit(tanh(s+b)*pi) (1 thread/row, 512 waves, ~2 us)
//   B  post:    out = z @ W_post.T + b_post     (write-streamer, W tile in regs,
//                                                uniform z loads -> no store/load vmcnt coupling)
// z staged in d_ws (512 KB). Fallback to fused kernel if ws is too small.

namespace {

constexpr int   kB        = 32768;
constexpr int   kDin      = 2048;
constexpr int   kDout     = 2048;
constexpr float kPi       = 3.14159265358979323846f;
constexpr float kInvSqrt2 = 0.70710678118654752440f;

__device__ __forceinline__ float2 cmul(float2 a, float2 b) {
    return make_float2(a.x * b.x - a.y * b.y, a.x * b.y + a.y * b.x);
}

// ---------------------------------------------------------------------------
// Kernel A: s[row][c] = <x_row, W_pre_c>   (no bias/tanh here)
// 4 rows per wave so each W_pre load is reused 4x (W L2 traffic /4).
// ---------------------------------------------------------------------------
__global__ __launch_bounds__(256) void dots_kernel(
    const float* __restrict__ x,      // (B, 2048)
    const float* __restrict__ W_pre,  // (4, 2048)
    float*       __restrict__ s_out)  // (B, 4)  [workspace]
{
    const int lane = threadIdx.x & 63;
    const int wv   = threadIdx.x >> 6;
    const int row0 = ((blockIdx.x << 2) + wv) << 2;   // 4 rows per wave; grid = B/16

    float acc[4][4];
#pragma unroll
    for (int r = 0; r < 4; ++r)
#pragma unroll
        for (int c = 0; c < 4; ++c) acc[r][c] = 0.f;

#pragma unroll
    for (int it = 0; it < kDin / 256; ++it) {          // 8 iterations
        const int k = it * 256 + lane * 4;
        const float4 w0 = *(const float4*)(W_pre + 0 * kDin + k);
        const float4 w1 = *(const float4*)(W_pre + 1 * kDin + k);
        const float4 w2 = *(const float4*)(W_pre + 2 * kDin + k);
        const float4 w3 = *(const float4*)(W_pre + 3 * kDin + k);
#pragma unroll
        for (int r = 0; r < 4; ++r) {
            const float4 xv = *(const float4*)(x + (size_t)(row0 + r) * kDin + k);
            acc[r][0] += xv.x * w0.x + xv.y * w0.y + xv.z * w0.z + xv.w * w0.w;
            acc[r][1] += xv.x * w1.x + xv.y * w1.y + xv.z * w1.z + xv.w * w1.w;
            acc[r][2] += xv.x * w2.x + xv.y * w2.y + xv.z * w2.z + xv.w * w2.w;
            acc[r][3] += xv.x * w3.x + xv.y * w3.y + xv.z * w3.z + xv.w * w3.w;
        }
    }

    // butterfly: every lane ends with full sums (16 values)
#pragma unroll
    for (int off = 32; off > 0; off >>= 1) {
#pragma unroll
        for (int r = 0; r < 4; ++r)
#pragma unroll
            for (int c = 0; c < 4; ++c) acc[r][c] += __shfl_xor(acc[r][c], off);
    }

    if (lane < 4) {
        *(float4*)(s_out + (size_t)(row0 + lane) * 4) =
            make_float4(acc[lane][0], acc[lane][1], acc[lane][2], acc[lane][3]);
    }
}

// ---------------------------------------------------------------------------
// Kernel A2: z[row] = measure(circuit(tanh(s+b_pre)*pi)), one thread per row.
// In-place over the s buffer. 32768 threads = 512 waves -> ~2 us.
// ---------------------------------------------------------------------------
__global__ __launch_bounds__(256) void circuit_kernel(
    float*       __restrict__ sz,     // (B, 4) in: s, out: z
    const float* __restrict__ b_pre,  // (4,)
    const float* __restrict__ qw)     // (2, 4, 3)
{
    const int row = blockIdx.x * 256 + threadIdx.x;
    const float4 sv = *(const float4*)(sz + (size_t)row * 4);
    float av[4] = { tanhf(sv.x + b_pre[0]) * kPi,
                    tanhf(sv.y + b_pre[1]) * kPi,
                    tanhf(sv.z + b_pre[2]) * kPi,
                    tanhf(sv.w + b_pre[3]) * kPi };

    float2 st[16];
#pragma unroll
    for (int i = 0; i < 16; ++i) st[i] = make_float2(0.f, 0.f);
    st[0] = make_float2(1.f, 0.f);

    // Encoding: per qubit q apply M = RZ(atan(f^2)) * RY(atan(f)) * H
#pragma unroll
    for (int q = 0; q < 4; ++q) {
        const int bq = 1 << q;
        const float f = av[q];
        float sr, cr;  sincosf(0.5f * atanf(f),     &sr, &cr);
        float sz_, cz; sincosf(0.5f * atanf(f * f), &sz_, &cz);
        const float u = kInvSqrt2 * (cr - sr);
        const float v = kInvSqrt2 * (cr + sr);
        const float2 e  = make_float2(cz, -sz_);
        const float2 ec = make_float2(cz,  sz_);
#pragma unroll
        for (int idx = 0; idx < 16; ++idx) {
            if (idx & bq) continue;
            const float2 a0 = st[idx], a1 = st[idx | bq];
            const float2 t0 = make_float2(u * a0.x + v * a1.x, u * a0.y + v * a1.y);
            const float2 t1 = make_float2(v * a0.x - u * a1.x, v * a0.y - u * a1.y);
            st[idx]      = cmul(e,  t0);
            st[idx | bq] = cmul(ec, t1);
        }
    }

    // Entangling layers
#pragma unroll
    for (int l = 0; l < 2; ++l) {
#pragma unroll
        for (int c = 0; c < 4; ++c) {
            const int t  = (c + 1) & 3;
            const int bc = 1 << c, bt = 1 << t;
#pragma unroll
            for (int idx = 0; idx < 16; ++idx) {
                if ((idx & bc) && !(idx & bt)) {
                    const float2 tmp = st[idx];
                    st[idx]      = st[idx | bt];
                    st[idx | bt] = tmp;
                }
            }
        }
#pragma unroll
        for (int q = 0; q < 4; ++q) {
            const int bq = 1 << q;
            const float phi = qw[l * 12 + q * 3 + 0];
            const float th  = qw[l * 12 + q * 3 + 1];
            const float om  = qw[l * 12 + q * 3 + 2];
            float s2, c2;  sincosf(0.5f * th,         &s2, &c2);
            float sp, cp;  sincosf(0.5f * (phi + om), &sp, &cp);
            float sm, cm;  sincosf(0.5f * (phi - om), &sm, &cm);
            const float2 m00 = make_float2( cp * c2, -sp * c2);
            const float2 m01 = make_float2(-cm * s2, -sm * s2);
            const float2 m10 = make_float2( cm * s2, -sm * s2);
            const float2 m11 = make_float2( cp * c2,  sp * c2);
#pragma unroll
            for (int idx = 0; idx < 16; ++idx) {
                if (idx & bq) continue;
                const float2 a0 = st[idx], a1 = st[idx | bq];
                float2 n0 = cmul(m00, a0), u01 = cmul(m01, a1);
                n0.x += u01.x; n0.y += u01.y;
                float2 n1 = cmul(m10, a0), u11 = cmul(m11, a1);
                n1.x += u11.x; n1.y += u11.y;
                st[idx]      = n0;
                st[idx | bq] = n1;
            }
        }
    }

    float z[4] = {0.f, 0.f, 0.f, 0.f};
#pragma unroll
    for (int idx = 0; idx < 16; ++idx) {
        const float p = st[idx].x * st[idx].x + st[idx].y * st[idx].y;
#pragma unroll
        for (int w = 0; w < 4; ++w) z[w] += (idx & (1 << w)) ? -p : p;
    }
    *(float4*)(sz + (size_t)row * 4) = make_float4(z[0], z[1], z[2], z[3]);
}

// ---------------------------------------------------------------------------
// Kernel B: out[row][j] = z[row] . W_post[j] + b_post[j]
// Block owns a 1024-column tile (W/b in regs for the whole block) x 32 rows.
// Per row: one UNIFORM z load (scalar path, no vmcnt-coupling with stores)
// + one float4 store per lane -> stores stream back-to-back.
// ---------------------------------------------------------------------------
__global__ __launch_bounds__(256) void post_kernel(
    const float* __restrict__ z,      // (B, 4)  [workspace]
    const float* __restrict__ W_post, // (2048, 4)
    const float* __restrict__ b_post, // (2048,)
    float*       __restrict__ out)    // (B, 2048)
{
    const int tid  = threadIdx.x;
    const int jt   = blockIdx.x & 1;           // column tile: 0 or 1
    const int rb   = blockIdx.x >> 1;          // row block
    const int j    = jt * 1024 + tid * 4;
    const int row0 = rb * 32;

    const float4 wa = *(const float4*)(W_post + (size_t)j * 4);
    const float4 wb = *(const float4*)(W_post + (size_t)j * 4 + 4);
    const float4 wc = *(const float4*)(W_post + (size_t)j * 4 + 8);
    const float4 wd = *(const float4*)(W_post + (size_t)j * 4 + 12);
    const float4 bp = *(const float4*)(b_post + j);

    float* obase = out + (size_t)row0 * kDout + j;
#pragma unroll 8
    for (int r = 0; r < 32; ++r) {
        const float4 zv = *(const float4*)(z + (size_t)(row0 + r) * 4);  // uniform across block
        float4 o;
        o.x = zv.x * wa.x + zv.y * wa.y + zv.z * wa.z + zv.w * wa.w + bp.x;
        o.y = zv.x * wb.x + zv.y * wb.y + zv.z * wb.z + zv.w * wb.w + bp.y;
        o.z = zv.x * wc.x + zv.y * wc.y + zv.z * wc.z + zv.w * wc.w + bp.z;
        o.w = zv.x * wd.x + zv.y * wd.y + zv.z * wd.z + zv.w * wd.w + bp.w;
        *(float4*)(obase + (size_t)r * kDout) = o;
    }
}

// ---------------------------------------------------------------------------
// Fallback: previous fused kernel (used only if workspace < 512 KB).
// ---------------------------------------------------------------------------
__global__ __launch_bounds__(256) void qproj_fused(
    const float* __restrict__ x, const float* __restrict__ W_pre,
    const float* __restrict__ b_pre, const float* __restrict__ qw,
    const float* __restrict__ W_post, const float* __restrict__ b_post,
    float* __restrict__ out)
{
    const int lane = threadIdx.x & 63;
    const int wv   = threadIdx.x >> 6;
    const int row0 = ((blockIdx.x << 2) + wv) * 8;

    float my_s[4] = {0.f, 0.f, 0.f, 0.f};
#pragma unroll 1
    for (int r = 0; r < 8; ++r) {
        const float* xrow = x + (size_t)(row0 + r) * kDin;
        float acc[4] = {0.f, 0.f, 0.f, 0.f};
#pragma unroll
        for (int it = 0; it < kDin / 256; ++it) {
            const int k = it * 256 + lane * 4;
            const float4 xv = *(const float4*)(xrow + k);
            const float4 w0 = *(const float4*)(W_pre + 0 * kDin + k);
            const float4 w1 = *(const float4*)(W_pre + 1 * kDin + k);
            const float4 w2 = *(const float4*)(W_pre + 2 * kDin + k);
            const float4 w3 = *(const float4*)(W_pre + 3 * kDin + k);
            acc[0] += xv.x * w0.x + xv.y * w0.y + xv.z * w0.z + xv.w * w0.w;
            acc[1] += xv.x * w1.x + xv.y * w1.y + xv.z * w1.z + xv.w * w1.w;
            acc[2] += xv.x * w2.x + xv.y * w2.y + xv.z * w2.z + xv.w * w2.w;
            acc[3] += xv.x * w3.x + xv.y * w3.y + xv.z * w3.z + xv.w * w3.w;
        }
#pragma unroll
        for (int off = 32; off > 0; off >>= 1)
#pragma unroll
            for (int i = 0; i < 4; ++i) acc[i] += __shfl_xor(acc[i], off);
        if (lane == r)
#pragma unroll
            for (int i = 0; i < 4; ++i) my_s[i] = acc[i];
    }

    float av[4];
#pragma unroll
    for (int i = 0; i < 4; ++i) av[i] = tanhf(my_s[i] + b_pre[i]) * kPi;

    float2 st[16];
#pragma unroll
    for (int i = 0; i < 16; ++i) st[i] = make_float2(0.f, 0.f);
    st[0] = make_float2(1.f, 0.f);
#pragma unroll
    for (int q = 0; q < 4; ++q) {
        const int bq = 1 << q;
        const float f = av[q];
        float sr, cr;  sincosf(0.5f * atanf(f),     &sr, &cr);
        float sz, cz;  sincosf(0.5f * atanf(f * f), &sz, &cz);
        const float u = kInvSqrt2 * (cr - sr);
        const float v = kInvSqrt2 * (cr + sr);
        const float2 e  = make_float2(cz, -sz);
        const float2 ec = make_float2(cz,  sz);
#pragma unroll
        for (int idx = 0; idx < 16; ++idx) {
            if (idx & bq) continue;
            const float2 a0 = st[idx], a1 = st[idx | bq];
            const float2 t0 = make_float2(u * a0.x + v * a1.x, u * a0.y + v * a1.y);
            const float2 t1 = make_float2(v * a0.x - u * a1.x, v * a0.y - u * a1.y);
            st[idx]      = cmul(e,  t0);
            st[idx | bq] = cmul(ec, t1);
        }
    }
#pragma unroll
    for (int l = 0; l < 2; ++l) {
#pragma unroll
        for (int c = 0; c < 4; ++c) {
            const int t  = (c + 1) & 3;
            const int bc = 1 << c, bt = 1 << t;
#pragma unroll
            for (int idx = 0; idx < 16; ++idx) {
                if ((idx & bc) && !(idx & bt)) {
                    const float2 tmp = st[idx];
                    st[idx]      = st[idx | bt];
                    st[idx | bt] = tmp;
                }
            }
        }
#pragma unroll
        for (int q = 0; q < 4; ++q) {
            const int bq = 1 << q;
            const float phi = qw[l * 12 + q * 3 + 0];
            const float th  = qw[l * 12 + q * 3 + 1];
            const float om  = qw[l * 12 + q * 3 + 2];
            float s2, c2;  sincosf(0.5f * th,         &s2, &c2);
            float sp, cp;  sincosf(0.5f * (phi + om), &sp, &cp);
            float sm, cm;  sincosf(0.5f * (phi - om), &sm, &cm);
            const float2 m00 = make_float2( cp * c2, -sp * c2);
            const float2 m01 = make_float2(-cm * s2, -sm * s2);
            const float2 m10 = make_float2( cm * s2, -sm * s2);
            const float2 m11 = make_float2( cp * c2,  sp * c2);
#pragma unroll
            for (int idx = 0; idx < 16; ++idx) {
                if (idx & bq) continue;
                const float2 a0 = st[idx], a1 = st[idx | bq];
                float2 n0 = cmul(m00, a0), u01 = cmul(m01, a1);
                n0.x += u01.x; n0.y += u01.y;
                float2 n1 = cmul(m10, a0), u11 = cmul(m11, a1);
                n1.x += u11.x; n1.y += u11.y;
                st[idx]      = n0;
                st[idx | bq] = n1;
            }
        }
    }
    float z[4] = {0.f, 0.f, 0.f, 0.f};
#pragma unroll
    for (int idx = 0; idx < 16; ++idx) {
        const float p = st[idx].x * st[idx].x + st[idx].y * st[idx].y;
#pragma unroll
        for (int w = 0; w < 4; ++w) z[w] += (idx & (1 << w)) ? -p : p;
    }
    float zb[8][4];
#pragma unroll
    for (int r = 0; r < 8; ++r)
#pragma unroll
        for (int c = 0; c < 4; ++c) zb[r][c] = __shfl(z[c], r);

    float* obase = out + (size_t)row0 * kDout;
#pragma unroll 1
    for (int it = 0; it < kDout / 256; ++it) {
        const int j = it * 256 + lane * 4;
        const float4 bp = *(const float4*)(b_post + j);
        const float4 wa = *(const float4*)(W_post + (size_t)(j + 0) * 4);
        const float4 wb = *(const float4*)(W_post + (size_t)(j + 1) * 4);
        const float4 wc = *(const float4*)(W_post + (size_t)(j + 2) * 4);
        const float4 wd = *(const float4*)(W_post + (size_t)(j + 3) * 4);
#pragma unroll
        for (int r = 0; r < 8; ++r) {
            float4 o;
            o.x = zb[r][0] * wa.x + zb[r][1] * wa.y + zb[r][2] * wa.z + zb[r][3] * wa.w + bp.x;
            o.y = zb[r][0] * wb.x + zb[r][1] * wb.y + zb[r][2] * wb.z + zb[r][3] * wb.w + bp.y;
            o.z = zb[r][0] * wc.x + zb[r][1] * wc.y + zb[r][2] * wc.z + zb[r][3] * wc.w + bp.z;
            o.w = zb[r][0] * wd.x + zb[r][1] * wd.y + zb[r][2] * wd.z + zb[r][3] * wd.w + bp.w;
            *(float4*)(obase + (size_t)r * kDout + j) = o;
        }
    }
}

} // namespace

extern "C" void kernel_launch(void* const* d_in, const int* in_sizes, int n_in,
                              void* d_out, int out_size, void* d_ws, size_t ws_size,
                              hipStream_t stream) {
    const float* x      = (const float*)d_in[0];
    const float* W_pre  = (const float*)d_in[1];
    const float* b_pre  = (const float*)d_in[2];
    const float* qw     = (const float*)d_in[3];
    const float* W_post = (const float*)d_in[4];
    const float* b_post = (const float*)d_in[5];
    float* out = (float*)d_out;

    const size_t z_bytes = (size_t)kB * 4 * sizeof(float);   // 512 KB
    if (d_ws != nullptr && ws_size >= z_bytes) {
        float* sz = (float*)d_ws;
        // A: dots -> s  (4 rows/wave, 16 rows/block -> 2048 blocks)
        dots_kernel<<<dim3(kB / 16), dim3(256), 0, stream>>>(x, W_pre, sz);
        // A2: circuit in-place s -> z  (128 blocks)
        circuit_kernel<<<dim3(kB / 256), dim3(256), 0, stream>>>(sz, b_pre, qw);
        // B: out = z @ W_post.T + b_post  (2 col tiles x 1024 row blocks -> 2048 blocks)
        post_kernel<<<dim3(2 * (kB / 32)), dim3(256), 0, stream>>>(sz, W_post, b_post, out);
    } else {
        qproj_fused<<<dim3(kB / 32), dim3(256), 0, stream>>>(
            x, W_pre, b_pre, qw, W_post, b_post, out);
    }
}

// Round 3
// 467.022 us; speedup vs baseline: 1.0733x; 1.0733x over previous
//
#include <hip/hip_runtime.h>
#include <cmath>

// QuantumProjection: out = (tanh(x @ W_pre.T + b_pre)*pi -> 4-qubit circuit -> z) @ W_post.T + b_post
// B=32768, D_IN=D_OUT=2048, N_QUBITS=4, N_LAYERS=2. Pure fp32.
// Traffic floor: 268 MB read (x) + 268 MB write (out) -> ~85 us @ 6.3 TB/s.
//
// R3: two kernels.
//   A dots+circuit: 8 rows/wave dot products (butterfly reduce), circuit fused in
//     the wave tail (lanes 0-7 own one row each) -> z[B][4] in workspace.
//     Kills the separate circuit dispatch and the s round-trip.
//   B post: z staged in LDS once per block (ds_read decoupled from store vmcnt
//     FIFO -> stores stream back-to-back), W_post tile in regs, NONTEMPORAL
//     stores (out never re-read; keeps L3 for x residency).
// Harness calibration: fillBuffer streams writes at 6.5 TB/s -> post target ~45 us.

namespace {

constexpr int   kB        = 32768;
constexpr int   kDin      = 2048;
constexpr int   kDout     = 2048;
constexpr float kPi       = 3.14159265358979323846f;
constexpr float kInvSqrt2 = 0.70710678118654752440f;

typedef float vfloat4 __attribute__((ext_vector_type(4)));

__device__ __forceinline__ float2 cmul(float2 a, float2 b) {
    return make_float2(a.x * b.x - a.y * b.y, a.x * b.y + a.y * b.x);
}

// Shared circuit: av[4] (encoded angles already tanh*pi) -> z[4]
__device__ __forceinline__ void run_circuit(const float av[4],
                                            const float* __restrict__ qw,
                                            float z[4]) {
    float2 st[16];
#pragma unroll
    for (int i = 0; i < 16; ++i) st[i] = make_float2(0.f, 0.f);
    st[0] = make_float2(1.f, 0.f);

    // Encoding: per qubit q apply M = RZ(atan(f^2)) * RY(atan(f)) * H
#pragma unroll
    for (int q = 0; q < 4; ++q) {
        const int bq = 1 << q;
        const float f = av[q];
        float sr, cr;  sincosf(0.5f * atanf(f),     &sr, &cr);
        float sz_, cz; sincosf(0.5f * atanf(f * f), &sz_, &cz);
        const float u = kInvSqrt2 * (cr - sr);
        const float v = kInvSqrt2 * (cr + sr);
        const float2 e  = make_float2(cz, -sz_);
        const float2 ec = make_float2(cz,  sz_);
#pragma unroll
        for (int idx = 0; idx < 16; ++idx) {
            if (idx & bq) continue;
            const float2 a0 = st[idx], a1 = st[idx | bq];
            const float2 t0 = make_float2(u * a0.x + v * a1.x, u * a0.y + v * a1.y);
            const float2 t1 = make_float2(v * a0.x - u * a1.x, v * a0.y - u * a1.y);
            st[idx]      = cmul(e,  t0);
            st[idx | bq] = cmul(ec, t1);
        }
    }

    // Entangling layers
#pragma unroll
    for (int l = 0; l < 2; ++l) {
#pragma unroll
        for (int c = 0; c < 4; ++c) {
            const int t  = (c + 1) & 3;
            const int bc = 1 << c, bt = 1 << t;
#pragma unroll
            for (int idx = 0; idx < 16; ++idx) {
                if ((idx & bc) && !(idx & bt)) {
                    const float2 tmp = st[idx];
                    st[idx]      = st[idx | bt];
                    st[idx | bt] = tmp;
                }
            }
        }
#pragma unroll
        for (int q = 0; q < 4; ++q) {
            const int bq = 1 << q;
            const float phi = qw[l * 12 + q * 3 + 0];
            const float th  = qw[l * 12 + q * 3 + 1];
            const float om  = qw[l * 12 + q * 3 + 2];
            float s2, c2;  sincosf(0.5f * th,         &s2, &c2);
            float sp, cp;  sincosf(0.5f * (phi + om), &sp, &cp);
            float sm, cm;  sincosf(0.5f * (phi - om), &sm, &cm);
            const float2 m00 = make_float2( cp * c2, -sp * c2);
            const float2 m01 = make_float2(-cm * s2, -sm * s2);
            const float2 m10 = make_float2( cm * s2, -sm * s2);
            const float2 m11 = make_float2( cp * c2,  sp * c2);
#pragma unroll
            for (int idx = 0; idx < 16; ++idx) {
                if (idx & bq) continue;
                const float2 a0 = st[idx], a1 = st[idx | bq];
                float2 n0 = cmul(m00, a0), u01 = cmul(m01, a1);
                n0.x += u01.x; n0.y += u01.y;
                float2 n1 = cmul(m10, a0), u11 = cmul(m11, a1);
                n1.x += u11.x; n1.y += u11.y;
                st[idx]      = n0;
                st[idx | bq] = n1;
            }
        }
    }

    z[0] = z[1] = z[2] = z[3] = 0.f;
#pragma unroll
    for (int idx = 0; idx < 16; ++idx) {
        const float p = st[idx].x * st[idx].x + st[idx].y * st[idx].y;
#pragma unroll
        for (int w = 0; w < 4; ++w) z[w] += (idx & (1 << w)) ? -p : p;
    }
}

// ---------------------------------------------------------------------------
// Kernel A: z[row] = circuit(tanh(x_row @ W_pre.T + b_pre)*pi)
// 8 rows per wave: W_pre loads amortized 8x. Butterfly -> lane r owns row r.
// All 64 lanes run the circuit (lanes >= 8 on garbage, discarded at the write).
// ---------------------------------------------------------------------------
__global__ __launch_bounds__(256) void dots_circuit_kernel(
    const float* __restrict__ x,      // (B, 2048)
    const float* __restrict__ W_pre,  // (4, 2048)
    const float* __restrict__ b_pre,  // (4,)
    const float* __restrict__ qw,     // (2, 4, 3)
    float*       __restrict__ z_out)  // (B, 4)  [workspace]
{
    const int lane = threadIdx.x & 63;
    const int wv   = threadIdx.x >> 6;
    const int row0 = (((blockIdx.x << 2) + wv) << 3);   // 8 rows/wave; grid = B/32

    float acc[8][4];
#pragma unroll
    for (int r = 0; r < 8; ++r)
#pragma unroll
        for (int c = 0; c < 4; ++c) acc[r][c] = 0.f;

#pragma unroll 2
    for (int it = 0; it < kDin / 256; ++it) {          // 8 iterations
        const int k = it * 256 + lane * 4;
        const float4 w0 = *(const float4*)(W_pre + 0 * kDin + k);
        const float4 w1 = *(const float4*)(W_pre + 1 * kDin + k);
        const float4 w2 = *(const float4*)(W_pre + 2 * kDin + k);
        const float4 w3 = *(const float4*)(W_pre + 3 * kDin + k);
#pragma unroll
        for (int r = 0; r < 8; ++r) {
            const float4 xv = *(const float4*)(x + (size_t)(row0 + r) * kDin + k);
            acc[r][0] += xv.x * w0.x + xv.y * w0.y + xv.z * w0.z + xv.w * w0.w;
            acc[r][1] += xv.x * w1.x + xv.y * w1.y + xv.z * w1.z + xv.w * w1.w;
            acc[r][2] += xv.x * w2.x + xv.y * w2.y + xv.z * w2.z + xv.w * w2.w;
            acc[r][3] += xv.x * w3.x + xv.y * w3.y + xv.z * w3.z + xv.w * w3.w;
        }
    }

    // butterfly: every lane ends with all 32 sums
#pragma unroll
    for (int off = 32; off > 0; off >>= 1) {
#pragma unroll
        for (int r = 0; r < 8; ++r)
#pragma unroll
            for (int c = 0; c < 4; ++c) acc[r][c] += __shfl_xor(acc[r][c], off);
    }

    // lane r (r < 8) takes row r's sums (compile-time indices only)
    float my_s[4] = {0.f, 0.f, 0.f, 0.f};
#pragma unroll
    for (int rr = 0; rr < 8; ++rr) {
        if (lane == rr) {
#pragma unroll
            for (int c = 0; c < 4; ++c) my_s[c] = acc[rr][c];
        }
    }

    float av[4];
#pragma unroll
    for (int c = 0; c < 4; ++c) av[c] = tanhf(my_s[c] + b_pre[c]) * kPi;

    float z[4];
    run_circuit(av, qw, z);

    if (lane < 8) {
        *(float4*)(z_out + (size_t)(row0 + lane) * 4) =
            make_float4(z[0], z[1], z[2], z[3]);
    }
}

// ---------------------------------------------------------------------------
// Kernel B: out[row][j] = z[row] . W_post[j] + b_post[j]
// z staged in LDS (ds_read path, decoupled from the store vmcnt FIFO) so the
// 32 nontemporal stores per thread stream with no intervening waits.
// ---------------------------------------------------------------------------
__global__ __launch_bounds__(256) void post_kernel(
    const float* __restrict__ z,      // (B, 4)  [workspace]
    const float* __restrict__ W_post, // (2048, 4)
    const float* __restrict__ b_post, // (2048,)
    float*       __restrict__ out)    // (B, 2048)
{
    const int tid  = threadIdx.x;
    const int jt   = blockIdx.x & 1;           // column tile: 0 or 1
    const int rb   = blockIdx.x >> 1;          // row block
    const int j    = jt * 1024 + tid * 4;
    const int row0 = rb * 32;

    __shared__ float4 zsh[32];

    // issue W/b loads first, then the tiny z stage
    const float4 wa = *(const float4*)(W_post + (size_t)j * 4);
    const float4 wb = *(const float4*)(W_post + (size_t)j * 4 + 4);
    const float4 wc = *(const float4*)(W_post + (size_t)j * 4 + 8);
    const float4 wd = *(const float4*)(W_post + (size_t)j * 4 + 12);
    const float4 bp = *(const float4*)(b_post + j);

    if (tid < 32) zsh[tid] = *(const float4*)(z + (size_t)(row0 + tid) * 4);
    __syncthreads();

    float* obase = out + (size_t)row0 * kDout + j;
#pragma unroll
    for (int r = 0; r < 32; ++r) {
        const float4 zv = zsh[r];              // LDS broadcast (lgkmcnt, not vmcnt)
        vfloat4 o;
        o.x = zv.x * wa.x + zv.y * wa.y + zv.z * wa.z + zv.w * wa.w + bp.x;
        o.y = zv.x * wb.x + zv.y * wb.y + zv.z * wb.z + zv.w * wb.w + bp.y;
        o.z = zv.x * wc.x + zv.y * wc.y + zv.z * wc.z + zv.w * wc.w + bp.z;
        o.w = zv.x * wd.x + zv.y * wd.y + zv.z * wd.z + zv.w * wd.w + bp.w;
        __builtin_nontemporal_store(o, (vfloat4*)(obase + (size_t)r * kDout));
    }
}

// ---------------------------------------------------------------------------
// Fallback: fused kernel (used only if workspace < 512 KB). Known-correct.
// ---------------------------------------------------------------------------
__global__ __launch_bounds__(256) void qproj_fused(
    const float* __restrict__ x, const float* __restrict__ W_pre,
    const float* __restrict__ b_pre, const float* __restrict__ qw,
    const float* __restrict__ W_post, const float* __restrict__ b_post,
    float* __restrict__ out)
{
    const int lane = threadIdx.x & 63;
    const int wv   = threadIdx.x >> 6;
    const int row0 = ((blockIdx.x << 2) + wv) * 8;

    float my_s[4] = {0.f, 0.f, 0.f, 0.f};
#pragma unroll 1
    for (int r = 0; r < 8; ++r) {
        const float* xrow = x + (size_t)(row0 + r) * kDin;
        float acc[4] = {0.f, 0.f, 0.f, 0.f};
#pragma unroll
        for (int it = 0; it < kDin / 256; ++it) {
            const int k = it * 256 + lane * 4;
            const float4 xv = *(const float4*)(xrow + k);
            const float4 w0 = *(const float4*)(W_pre + 0 * kDin + k);
            const float4 w1 = *(const float4*)(W_pre + 1 * kDin + k);
            const float4 w2 = *(const float4*)(W_pre + 2 * kDin + k);
            const float4 w3 = *(const float4*)(W_pre + 3 * kDin + k);
            acc[0] += xv.x * w0.x + xv.y * w0.y + xv.z * w0.z + xv.w * w0.w;
            acc[1] += xv.x * w1.x + xv.y * w1.y + xv.z * w1.z + xv.w * w1.w;
            acc[2] += xv.x * w2.x + xv.y * w2.y + xv.z * w2.z + xv.w * w2.w;
            acc[3] += xv.x * w3.x + xv.y * w3.y + xv.z * w3.z + xv.w * w3.w;
        }
#pragma unroll
        for (int off = 32; off > 0; off >>= 1)
#pragma unroll
            for (int i = 0; i < 4; ++i) acc[i] += __shfl_xor(acc[i], off);
        if (lane == r)
#pragma unroll
            for (int i = 0; i < 4; ++i) my_s[i] = acc[i];
    }

    float av[4];
#pragma unroll
    for (int i = 0; i < 4; ++i) av[i] = tanhf(my_s[i] + b_pre[i]) * kPi;
    float z[4];
    run_circuit(av, qw, z);

    float zb[8][4];
#pragma unroll
    for (int r = 0; r < 8; ++r)
#pragma unroll
        for (int c = 0; c < 4; ++c) zb[r][c] = __shfl(z[c], r);

    float* obase = out + (size_t)row0 * kDout;
#pragma unroll 1
    for (int it = 0; it < kDout / 256; ++it) {
        const int j = it * 256 + lane * 4;
        const float4 bp = *(const float4*)(b_post + j);
        const float4 wa = *(const float4*)(W_post + (size_t)(j + 0) * 4);
        const float4 wb = *(const float4*)(W_post + (size_t)(j + 1) * 4);
        const float4 wc = *(const float4*)(W_post + (size_t)(j + 2) * 4);
        const float4 wd = *(const float4*)(W_post + (size_t)(j + 3) * 4);
#pragma unroll
        for (int r = 0; r < 8; ++r) {
            float4 o;
            o.x = zb[r][0] * wa.x + zb[r][1] * wa.y + zb[r][2] * wa.z + zb[r][3] * wa.w + bp.x;
            o.y = zb[r][0] * wb.x + zb[r][1] * wb.y + zb[r][2] * wb.z + zb[r][3] * wb.w + bp.y;
            o.z = zb[r][0] * wc.x + zb[r][1] * wc.y + zb[r][2] * wc.z + zb[r][3] * wc.w + bp.z;
            o.w = zb[r][0] * wd.x + zb[r][1] * wd.y + zb[r][2] * wd.z + zb[r][3] * wd.w + bp.w;
            *(float4*)(obase + (size_t)r * kDout + j) = o;
        }
    }
}

} // namespace

extern "C" void kernel_launch(void* const* d_in, const int* in_sizes, int n_in,
                              void* d_out, int out_size, void* d_ws, size_t ws_size,
                              hipStream_t stream) {
    const float* x      = (const float*)d_in[0];
    const float* W_pre  = (const float*)d_in[1];
    const float* b_pre  = (const float*)d_in[2];
    const float* qw     = (const float*)d_in[3];
    const float* W_post = (const float*)d_in[4];
    const float* b_post = (const float*)d_in[5];
    float* out = (float*)d_out;

    const size_t z_bytes = (size_t)kB * 4 * sizeof(float);   // 512 KB
    if (d_ws != nullptr && ws_size >= z_bytes) {
        float* zbuf = (float*)d_ws;
        // A: dots + circuit -> z  (8 rows/wave, 32 rows/block -> 1024 blocks)
        dots_circuit_kernel<<<dim3(kB / 32), dim3(256), 0, stream>>>(
            x, W_pre, b_pre, qw, zbuf);
        // B: out = z @ W_post.T + b_post  (2 col tiles x 1024 row blocks)
        post_kernel<<<dim3(2 * (kB / 32)), dim3(256), 0, stream>>>(
            zbuf, W_post, b_post, out);
    } else {
        qproj_fused<<<dim3(kB / 32), dim3(256), 0, stream>>>(
            x, W_pre, b_pre, qw, W_post, b_post, out);
    }
}